// Round 1
// baseline (901.485 us; speedup 1.0000x reference)
//
#include <hip/hip_runtime.h>

#define HW 65536
#define WD 256
#define HD 256
#define CC 32

__device__ __forceinline__ float frelu(float v){ return v > 0.f ? v : 0.f; }

// ---------------- weight prep: transpose w1, fold+transpose w2/w3 ----------------
// Storage block order in CAT: 0=up 1=right 2=down 3=left 4=diagDR(zuoxia==zuoshang) 5=diagDL(youxia) 6=diagUR(youshang)
__global__ void prep_weights(const float* __restrict__ w1,
                             const float* __restrict__ w2,
                             const float* __restrict__ w3,
                             float* __restrict__ wt1,   // [64][32]
                             float* __restrict__ wf2,   // [224][32]
                             float* __restrict__ wf3) { // [224][32]
    int t = threadIdx.x;
    for (int idx = t; idx < 64 * 32; idx += 256) {
        int i = idx >> 5, o = idx & 31;
        wt1[idx] = w1[o * 64 + i];
    }
    for (int idx = t; idx < 224 * 32; idx += 256) {
        int j = idx >> 5, o = idx & 31;
        int blk = j >> 5, i = j & 31;
        int base = o * 256;
        float v2, v3;
        if (blk < 4)        { v2 = w2[base + blk*32 + i];                     v3 = w3[base + blk*32 + i]; }
        else if (blk == 4)  { v2 = w2[base + 128 + i] + w2[base + 192 + i];   v3 = w3[base + 128 + i] + w3[base + 192 + i]; }
        else if (blk == 5)  { v2 = w2[base + 160 + i];                        v3 = w3[base + 160 + i]; }
        else                { v2 = w2[base + 224 + i];                        v3 = w3[base + 224 + i]; }
        wf2[idx] = v2;
        wf3[idx] = v3;
    }
}

// ---------------- generic 1x1 conv: [Kb][CIN][HW] -> [Kb][32][HW] ----------------
template<int CIN, bool RELU>
__global__ __launch_bounds__(256) void conv1x1_k(const float* __restrict__ in,
                                                 const float* __restrict__ wt,   // [CIN][32] transposed
                                                 const float* __restrict__ bias, // [32]
                                                 float* __restrict__ out) {
    int p = blockIdx.x * 256 + threadIdx.x;
    int b = blockIdx.y;
    const float* ip = in + (size_t)b * CIN * HW + p;
    float acc[32];
#pragma unroll
    for (int o = 0; o < 32; ++o) acc[o] = bias[o];
#pragma unroll 4
    for (int i = 0; i < CIN; ++i) {
        float v = ip[(size_t)i * HW];
        const float* wrow = wt + i * 32;
#pragma unroll
        for (int o = 0; o < 32; ++o) acc[o] = fmaf(wrow[o], v, acc[o]);
    }
    float* op = out + (size_t)b * 32 * HW + p;
#pragma unroll
    for (int o = 0; o < 32; ++o) op[(size_t)o * HW] = RELU ? frelu(acc[o]) : acc[o];
}

// ---------------- row scans (along h): down, diagDR, diagDL (fwd) / up, diagUR (bwd) ----------------
// grid: (32 channels, Kb, 2 passes), 256 threads = one per column w
__global__ __launch_bounds__(256) void row_scan_k(const float* __restrict__ F,   // [Kb][32][HW]
                                                  float* __restrict__ CAT,       // [Kb][7][32][HW]
                                                  const float* __restrict__ irw) {
    int w = threadIdx.x;
    int c = blockIdx.x;
    int b = blockIdx.y;
    const float wd = irw[2];
    const float* x = F + ((size_t)b * 32 + c) * HW;
    size_t catbase = (size_t)b * 7 * 32 * HW + (size_t)c * HW;
    __shared__ float sh[2][2][WD];

    if (blockIdx.z == 0) {   // forward over h
        float* o_dn = CAT + catbase + (size_t)2 * 32 * HW;
        float* o_dr = CAT + catbase + (size_t)4 * 32 * HW;
        float* o_dl = CAT + catbase + (size_t)5 * 32 * HW;
        float xv = x[w];
        float s_dn = xv;
        o_dn[w] = xv; o_dr[w] = xv; o_dl[w] = xv;
        sh[0][0][w] = xv; sh[0][1][w] = xv;
        __syncthreads();
        for (int h = 1; h < HD; ++h) {
            float xn = x[h * WD + w];
            int pb = (h - 1) & 1, cb = h & 1;
            s_dn = frelu(fmaf(s_dn, wd, xn));
            float sdr = (w == 0)      ? xn : frelu(fmaf(sh[pb][0][w - 1], wd, xn));
            float sdl = (w == WD - 1) ? xn : frelu(fmaf(sh[pb][1][w + 1], wd, xn));
            o_dn[h * WD + w] = s_dn;
            o_dr[h * WD + w] = sdr;
            o_dl[h * WD + w] = sdl;
            sh[cb][0][w] = sdr; sh[cb][1][w] = sdl;
            __syncthreads();
        }
    } else {                 // backward over h
        const float wu = irw[0];
        float* o_up = CAT + catbase + (size_t)0 * 32 * HW;
        float* o_ur = CAT + catbase + (size_t)6 * 32 * HW;
        float xv = x[(HD - 1) * WD + w];
        float s_up = xv;
        o_up[(HD - 1) * WD + w] = xv;
        o_ur[(HD - 1) * WD + w] = xv;
        sh[(HD - 1) & 1][0][w] = xv;
        __syncthreads();
        for (int h = HD - 2; h >= 0; --h) {
            float xn = x[h * WD + w];
            int pb = (h + 1) & 1, cb = h & 1;
            s_up = frelu(fmaf(s_up, wu, xn));
            float sur = (w == 0) ? xn : frelu(fmaf(sh[pb][0][w - 1], wd, xn));
            o_up[h * WD + w] = s_up;
            o_ur[h * WD + w] = sur;
            sh[cb][0][w] = sur;
            __syncthreads();
        }
    }
}

// ---------------- col scans (along w): right (fwd) / left (bwd), LDS-tiled ----------------
// grid: (32 channels, Kb, 2 dirs), 256 threads = one per row h
__global__ __launch_bounds__(256) void col_scan_k(const float* __restrict__ F,
                                                  float* __restrict__ CAT,
                                                  const float* __restrict__ irw) {
    int t = threadIdx.x;    // row index h
    int c = blockIdx.x;
    int b = blockIdx.y;
    int dir = blockIdx.z;   // 0=right, 1=left
    const float wgt = (dir == 0) ? irw[1] : irw[3];
    const float* x = F + ((size_t)b * 32 + c) * HW;
    float* o = CAT + ((size_t)b * 7 + (dir == 0 ? 1 : 3)) * 32 * HW + (size_t)c * HW;
    __shared__ float tile[256 * 33];
    float carry = 0.f;
    for (int tw = 0; tw < 8; ++tw) {
        int wbase = (dir == 0) ? tw * 32 : (7 - tw) * 32;
        __syncthreads();   // previous store must be done before tile reuse
#pragma unroll
        for (int k = 0; k < 32; ++k) {
            int lin = k * 256 + t;
            int hh = lin >> 5, ww = lin & 31;
            tile[hh * 33 + ww] = x[hh * WD + wbase + ww];
        }
        __syncthreads();
        if (dir == 0) {
#pragma unroll
            for (int j = 0; j < 32; ++j) {
                float xv = tile[t * 33 + j];
                carry = (wbase + j == 0) ? xv : frelu(fmaf(carry, wgt, xv));
                tile[t * 33 + j] = carry;
            }
        } else {
#pragma unroll
            for (int j = 31; j >= 0; --j) {
                float xv = tile[t * 33 + j];
                carry = (wbase + j == WD - 1) ? xv : frelu(fmaf(carry, wgt, xv));
                tile[t * 33 + j] = carry;
            }
        }
        __syncthreads();
#pragma unroll
        for (int k = 0; k < 32; ++k) {
            int lin = k * 256 + t;
            int hh = lin >> 5, ww = lin & 31;
            o[hh * WD + wbase + ww] = tile[hh * 33 + ww];
        }
    }
}

// ---------------- final 32->1 conv ----------------
__global__ __launch_bounds__(256) void conv_out_k(const float* __restrict__ in,  // [Kb][32][HW]
                                                  const float* __restrict__ wo,  // [32]
                                                  float* __restrict__ out) {     // [Kb][HW]
    int p = blockIdx.x * 256 + threadIdx.x;
    int b = blockIdx.y;
    const float* ip = in + (size_t)b * 32 * HW + p;
    float acc = 0.f;
#pragma unroll
    for (int o = 0; o < 32; ++o) acc = fmaf(wo[o], ip[(size_t)o * HW], acc);
    out[(size_t)b * HW + p] = acc;
}

extern "C" void kernel_launch(void* const* d_in, const int* in_sizes, int n_in,
                              void* d_out, int out_size, void* d_ws, size_t ws_size,
                              hipStream_t stream) {
    const float* x    = (const float*)d_in[0];
    const float* w1   = (const float*)d_in[1];
    const float* b1   = (const float*)d_in[2];
    const float* w2   = (const float*)d_in[3];
    const float* b2   = (const float*)d_in[4];
    const float* w3   = (const float*)d_in[5];
    const float* b3   = (const float*)d_in[6];
    const float* wout = (const float*)d_in[7];
    const float* ir1  = (const float*)d_in[8];
    const float* ir2  = (const float*)d_in[9];

    const size_t fbytes = (size_t)CC * HW * sizeof(float);  // 8 MB per batch-image
    const size_t wbytes = (64 * 32 + 2 * 224 * 32) * sizeof(float);

    // adaptive batch chunking on workspace size: need K*(2+7)*8MB + weights
    int K = 4;
    while (K > 1 && ((size_t)K * 9 * fbytes + wbytes) > ws_size) K >>= 1;

    char* ws = (char*)d_ws;
    float* F1  = (float*)ws;  ws += (size_t)K * fbytes;
    float* F2  = (float*)ws;  ws += (size_t)K * fbytes;
    float* CAT = (float*)ws;  ws += (size_t)K * 7 * fbytes;
    float* WT1 = (float*)ws;  ws += 64 * 32 * sizeof(float);
    float* WF2 = (float*)ws;  ws += 224 * 32 * sizeof(float);
    float* WF3 = (float*)ws;

    prep_weights<<<1, 256, 0, stream>>>(w1, w2, w3, WT1, WF2, WF3);

    for (int b0 = 0; b0 < 4; b0 += K) {
        // conv1: x (64ch) -> F1 (32ch), bias, no relu
        conv1x1_k<64, false><<<dim3(HW / 256, K), 256, 0, stream>>>(
            x + (size_t)b0 * 64 * HW, WT1, b1, F1);
        // irnn1 -> CAT (7 blocks)
        row_scan_k<<<dim3(32, K, 2), 256, 0, stream>>>(F1, CAT, ir1);
        col_scan_k<<<dim3(32, K, 2), 256, 0, stream>>>(F1, CAT, ir1);
        // conv2: CAT (224ch folded) -> F2, bias, no relu
        conv1x1_k<224, false><<<dim3(HW / 256, K), 256, 0, stream>>>(CAT, WF2, b2, F2);
        // irnn2 -> CAT
        row_scan_k<<<dim3(32, K, 2), 256, 0, stream>>>(F2, CAT, ir2);
        col_scan_k<<<dim3(32, K, 2), 256, 0, stream>>>(F2, CAT, ir2);
        // conv3: CAT -> F1 (reused), bias, RELU
        conv1x1_k<224, true><<<dim3(HW / 256, K), 256, 0, stream>>>(CAT, WF3, b3, F1);
        // conv_out: F1 -> mask
        conv_out_k<<<dim3(HW / 256, K), 256, 0, stream>>>(
            F1, wout, (float*)d_out + (size_t)b0 * HW);
    }
}

// Round 2
// 488.245 us; speedup vs baseline: 1.8464x; 1.8464x over previous
//
#include <hip/hip_runtime.h>

#define HW 65536
#define WD 256
#define HD 256
#define CC 32

__device__ __forceinline__ float frelu(float v){ return v > 0.f ? v : 0.f; }

// ---------------- weight prep: transpose w1, fold+transpose w2/w3 ----------------
// CAT block order: 0=up 1=right 2=down 3=left 4=diagDR(zuoxia==zuoshang) 5=diagDL(youxia) 6=diagUR(youshang)
__global__ void prep_weights(const float* __restrict__ w1,
                             const float* __restrict__ w2,
                             const float* __restrict__ w3,
                             float* __restrict__ wt1,   // [64][32]
                             float* __restrict__ wf2,   // [224][32]
                             float* __restrict__ wf3) { // [224][32]
    int t = threadIdx.x;
    for (int idx = t; idx < 64 * 32; idx += 256) {
        int i = idx >> 5, o = idx & 31;
        wt1[idx] = w1[o * 64 + i];
    }
    for (int idx = t; idx < 224 * 32; idx += 256) {
        int j = idx >> 5, o = idx & 31;
        int blk = j >> 5, i = j & 31;
        int base = o * 256;
        float v2, v3;
        if (blk < 4)        { v2 = w2[base + blk*32 + i];                     v3 = w3[base + blk*32 + i]; }
        else if (blk == 4)  { v2 = w2[base + 128 + i] + w2[base + 192 + i];   v3 = w3[base + 128 + i] + w3[base + 192 + i]; }
        else if (blk == 5)  { v2 = w2[base + 160 + i];                        v3 = w3[base + 160 + i]; }
        else                { v2 = w2[base + 224 + i];                        v3 = w3[base + 224 + i]; }
        wf2[idx] = v2;
        wf3[idx] = v3;
    }
}

// ---------------- generic 1x1 conv: [Kb][CIN][HW] -> [Kb][32][HW] ----------------
template<int CIN, bool RELU>
__global__ __launch_bounds__(256) void conv1x1_k(const float* __restrict__ in,
                                                 const float* __restrict__ wt,   // [CIN][32]
                                                 const float* __restrict__ bias, // [32]
                                                 float* __restrict__ out) {
    int p = blockIdx.x * 256 + threadIdx.x;
    int b = blockIdx.y;
    const float* ip = in + (size_t)b * CIN * HW + p;
    float acc[32];
#pragma unroll
    for (int o = 0; o < 32; ++o) acc[o] = bias[o];
#pragma unroll 4
    for (int i = 0; i < CIN; ++i) {
        float v = ip[(size_t)i * HW];
        const float* wrow = wt + i * 32;
#pragma unroll
        for (int o = 0; o < 32; ++o) acc[o] = fmaf(wrow[o], v, acc[o]);
    }
    float* op = out + (size_t)b * 32 * HW + p;
#pragma unroll
    for (int o = 0; o < 32; ++o) op[(size_t)o * HW] = RELU ? frelu(acc[o]) : acc[o];
}

// ---------------- row scans (along h): one wave per (c,b,dir), 4 cols/thread ----------------
// shfl for diagonal neighbor exchange, 8-deep prefetch ring, no barriers/LDS.
__global__ __launch_bounds__(64) void row_scan_k(const float* __restrict__ F,   // [Kb][32][HW]
                                                 float* __restrict__ CAT,       // [Kb][7][32][HW]
                                                 const float* __restrict__ irw) {
    int t = threadIdx.x;   // 0..63, owns cols 4t..4t+3
    int c = blockIdx.x;
    int b = blockIdx.y;
    const float wd = irw[2];
    const float4* xr = (const float4*)(F + ((size_t)b * 32 + c) * HW);
    size_t catbase = (size_t)b * 7 * 32 * HW + (size_t)c * HW;
    constexpr int D = 8;
    float4 buf[D];

    if (blockIdx.z == 0) {   // forward over h: down(2), diagDR(4), diagDL(5)
        float4* o_dn = (float4*)(CAT + catbase + (size_t)2 * 32 * HW);
        float4* o_dr = (float4*)(CAT + catbase + (size_t)4 * 32 * HW);
        float4* o_dl = (float4*)(CAT + catbase + (size_t)5 * 32 * HW);
        float4 x0 = xr[t];
        o_dn[t] = x0; o_dr[t] = x0; o_dl[t] = x0;
        float dn0=x0.x, dn1=x0.y, dn2=x0.z, dn3=x0.w;
        float dr0=x0.x, dr1=x0.y, dr2=x0.z, dr3=x0.w;
        float dl0=x0.x, dl1=x0.y, dl2=x0.z, dl3=x0.w;
#pragma unroll
        for (int j = 0; j < D; ++j) buf[j] = xr[(1 + j) * 64 + t];
        for (int hb = 1; hb < HD; hb += D) {
#pragma unroll
            for (int j = 0; j < D; ++j) {
                int h = hb + j;
                if (h < HD) {
                    float4 xv = buf[j];
                    int hn = h + D; if (hn > HD - 1) hn = HD - 1;
                    buf[j] = xr[hn * 64 + t];              // prefetch D rows ahead
                    float nbL = __shfl_up(dr3, 1);
                    float nbR = __shfl_down(dl0, 1);
                    dn0 = frelu(fmaf(dn0, wd, xv.x));
                    dn1 = frelu(fmaf(dn1, wd, xv.y));
                    dn2 = frelu(fmaf(dn2, wd, xv.z));
                    dn3 = frelu(fmaf(dn3, wd, xv.w));
                    float a0 = (t == 0) ? xv.x : frelu(fmaf(nbL, wd, xv.x));
                    float a1 = frelu(fmaf(dr0, wd, xv.y));
                    float a2 = frelu(fmaf(dr1, wd, xv.z));
                    float a3 = frelu(fmaf(dr2, wd, xv.w));
                    dr0 = a0; dr1 = a1; dr2 = a2; dr3 = a3;
                    float e0 = frelu(fmaf(dl1, wd, xv.x));
                    float e1 = frelu(fmaf(dl2, wd, xv.y));
                    float e2 = frelu(fmaf(dl3, wd, xv.z));
                    float e3 = (t == 63) ? xv.w : frelu(fmaf(nbR, wd, xv.w));
                    dl0 = e0; dl1 = e1; dl2 = e2; dl3 = e3;
                    o_dn[h * 64 + t] = make_float4(dn0, dn1, dn2, dn3);
                    o_dr[h * 64 + t] = make_float4(a0, a1, a2, a3);
                    o_dl[h * 64 + t] = make_float4(e0, e1, e2, e3);
                }
            }
        }
    } else {                 // backward over h: up(0), diagUR(6)
        const float wu = irw[0];
        float4* o_up = (float4*)(CAT + catbase + (size_t)0 * 32 * HW);
        float4* o_ur = (float4*)(CAT + catbase + (size_t)6 * 32 * HW);
        float4 x0 = xr[(HD - 1) * 64 + t];
        o_up[(HD - 1) * 64 + t] = x0; o_ur[(HD - 1) * 64 + t] = x0;
        float up0=x0.x, up1=x0.y, up2=x0.z, up3=x0.w;
        float ur0=x0.x, ur1=x0.y, ur2=x0.z, ur3=x0.w;
#pragma unroll
        for (int j = 0; j < D; ++j) buf[j] = xr[(HD - 2 - j) * 64 + t];
        for (int hb = HD - 2; hb >= 0; hb -= D) {
#pragma unroll
            for (int j = 0; j < D; ++j) {
                int h = hb - j;
                if (h >= 0) {
                    float4 xv = buf[j];
                    int hn = h - D; if (hn < 0) hn = 0;
                    buf[j] = xr[hn * 64 + t];
                    float nbL = __shfl_up(ur3, 1);
                    up0 = frelu(fmaf(up0, wu, xv.x));
                    up1 = frelu(fmaf(up1, wu, xv.y));
                    up2 = frelu(fmaf(up2, wu, xv.z));
                    up3 = frelu(fmaf(up3, wu, xv.w));
                    float a0 = (t == 0) ? xv.x : frelu(fmaf(nbL, wd, xv.x));
                    float a1 = frelu(fmaf(ur0, wd, xv.y));
                    float a2 = frelu(fmaf(ur1, wd, xv.z));
                    float a3 = frelu(fmaf(ur2, wd, xv.w));
                    ur0 = a0; ur1 = a1; ur2 = a2; ur3 = a3;
                    o_up[h * 64 + t] = make_float4(up0, up1, up2, up3);
                    o_ur[h * 64 + t] = make_float4(a0, a1, a2, a3);
                }
            }
        }
    }
}

// ---------------- col scans (along w): right(1)/left(3), LDS-tiled, double-buffered ----------------
// grid: (32 channels, Kb, 2 dirs), 256 threads = one per row h
__global__ __launch_bounds__(256) void col_scan_k(const float* __restrict__ F,
                                                  float* __restrict__ CAT,
                                                  const float* __restrict__ irw) {
    int t = threadIdx.x;
    int c = blockIdx.x;
    int b = blockIdx.y;
    int dir = blockIdx.z;   // 0=right, 1=left
    const float wgt = (dir == 0) ? irw[1] : irw[3];
    const float* x = F + ((size_t)b * 32 + c) * HW;
    float* o = CAT + ((size_t)b * 7 + (dir == 0 ? 1 : 3)) * 32 * HW + (size_t)c * HW;
    __shared__ float tile[256 * 33];
    int hh0 = t >> 5, ww = t & 31;   // load/store mapping: hh = k*8 + hh0
    float r[2][32];
    float carry = 0.f;
    {
        int wb0 = (dir == 0) ? 0 : 7 * 32;
#pragma unroll
        for (int k = 0; k < 32; ++k)
            r[0][k] = x[(k * 8 + hh0) * WD + wb0 + ww];
    }
#pragma unroll
    for (int tw = 0; tw < 8; ++tw) {
        int wbase = (dir == 0) ? tw * 32 : (7 - tw) * 32;
        const int cur = tw & 1, nxt = cur ^ 1;
        __syncthreads();           // previous store phase done reading LDS
#pragma unroll
        for (int k = 0; k < 32; ++k)
            tile[(k * 8 + hh0) * 33 + ww] = r[cur][k];
        __syncthreads();
        if (tw < 7) {              // prefetch next tile while scanning this one
            int wb2 = (dir == 0) ? (tw + 1) * 32 : (6 - tw) * 32;
#pragma unroll
            for (int k = 0; k < 32; ++k)
                r[nxt][k] = x[(k * 8 + hh0) * WD + wb2 + ww];
        }
        if (dir == 0) {
#pragma unroll
            for (int j = 0; j < 32; ++j) {
                float xv = tile[t * 33 + j];
                carry = (wbase + j == 0) ? xv : frelu(fmaf(carry, wgt, xv));
                tile[t * 33 + j] = carry;
            }
        } else {
#pragma unroll
            for (int j = 31; j >= 0; --j) {
                float xv = tile[t * 33 + j];
                carry = (wbase + j == WD - 1) ? xv : frelu(fmaf(carry, wgt, xv));
                tile[t * 33 + j] = carry;
            }
        }
        __syncthreads();
#pragma unroll
        for (int k = 0; k < 32; ++k)
            o[(k * 8 + hh0) * WD + wbase + ww] = tile[(k * 8 + hh0) * 33 + ww];
    }
}

// ---------------- final 32->1 conv ----------------
__global__ __launch_bounds__(256) void conv_out_k(const float* __restrict__ in,  // [Kb][32][HW]
                                                  const float* __restrict__ wo,  // [32]
                                                  float* __restrict__ out) {     // [Kb][HW]
    int p = blockIdx.x * 256 + threadIdx.x;
    int b = blockIdx.y;
    const float* ip = in + (size_t)b * 32 * HW + p;
    float acc = 0.f;
#pragma unroll
    for (int o = 0; o < 32; ++o) acc = fmaf(wo[o], ip[(size_t)o * HW], acc);
    out[(size_t)b * HW + p] = acc;
}

extern "C" void kernel_launch(void* const* d_in, const int* in_sizes, int n_in,
                              void* d_out, int out_size, void* d_ws, size_t ws_size,
                              hipStream_t stream) {
    const float* x    = (const float*)d_in[0];
    const float* w1   = (const float*)d_in[1];
    const float* b1   = (const float*)d_in[2];
    const float* w2   = (const float*)d_in[3];
    const float* b2   = (const float*)d_in[4];
    const float* w3   = (const float*)d_in[5];
    const float* b3   = (const float*)d_in[6];
    const float* wout = (const float*)d_in[7];
    const float* ir1  = (const float*)d_in[8];
    const float* ir2  = (const float*)d_in[9];

    const size_t fbytes = (size_t)CC * HW * sizeof(float);  // 8 MB per batch-image
    const size_t wbytes = (64 * 32 + 2 * 224 * 32) * sizeof(float);

    int K = 4;
    while (K > 1 && ((size_t)K * 9 * fbytes + wbytes) > ws_size) K >>= 1;

    char* ws = (char*)d_ws;
    float* F1  = (float*)ws;  ws += (size_t)K * fbytes;
    float* F2  = (float*)ws;  ws += (size_t)K * fbytes;
    float* CAT = (float*)ws;  ws += (size_t)K * 7 * fbytes;
    float* WT1 = (float*)ws;  ws += 64 * 32 * sizeof(float);
    float* WF2 = (float*)ws;  ws += 224 * 32 * sizeof(float);
    float* WF3 = (float*)ws;

    prep_weights<<<1, 256, 0, stream>>>(w1, w2, w3, WT1, WF2, WF3);

    for (int b0 = 0; b0 < 4; b0 += K) {
        conv1x1_k<64, false><<<dim3(HW / 256, K), 256, 0, stream>>>(
            x + (size_t)b0 * 64 * HW, WT1, b1, F1);
        row_scan_k<<<dim3(32, K, 2), 64, 0, stream>>>(F1, CAT, ir1);
        col_scan_k<<<dim3(32, K, 2), 256, 0, stream>>>(F1, CAT, ir1);
        conv1x1_k<224, false><<<dim3(HW / 256, K), 256, 0, stream>>>(CAT, WF2, b2, F2);
        row_scan_k<<<dim3(32, K, 2), 64, 0, stream>>>(F2, CAT, ir2);
        col_scan_k<<<dim3(32, K, 2), 256, 0, stream>>>(F2, CAT, ir2);
        conv1x1_k<224, true><<<dim3(HW / 256, K), 256, 0, stream>>>(CAT, WF3, b3, F1);
        conv_out_k<<<dim3(HW / 256, K), 256, 0, stream>>>(
            F1, wout, (float*)d_out + (size_t)b0 * HW);
    }
}

// Round 3
// 480.629 us; speedup vs baseline: 1.8756x; 1.0158x over previous
//
#include <hip/hip_runtime.h>

#define HW 65536
#define WD 256
#define HD 256
#define CC 32

__device__ __forceinline__ float frelu(float v){ return v > 0.f ? v : 0.f; }

// ---------------- weight prep: transpose w1, fold+transpose w2/w3 ----------------
// CAT block order: 0=up 1=right 2=down 3=left 4=diagDR(zuoxia==zuoshang) 5=diagDL(youxia) 6=diagUR(youshang)
__global__ void prep_weights(const float* __restrict__ w1,
                             const float* __restrict__ w2,
                             const float* __restrict__ w3,
                             float* __restrict__ wt1,   // [64][32]
                             float* __restrict__ wf2,   // [224][32]
                             float* __restrict__ wf3) { // [224][32]
    int t = threadIdx.x;
    for (int idx = t; idx < 64 * 32; idx += 256) {
        int i = idx >> 5, o = idx & 31;
        wt1[idx] = w1[o * 64 + i];
    }
    for (int idx = t; idx < 224 * 32; idx += 256) {
        int j = idx >> 5, o = idx & 31;
        int blk = j >> 5, i = j & 31;
        int base = o * 256;
        float v2, v3;
        if (blk < 4)        { v2 = w2[base + blk*32 + i];                     v3 = w3[base + blk*32 + i]; }
        else if (blk == 4)  { v2 = w2[base + 128 + i] + w2[base + 192 + i];   v3 = w3[base + 128 + i] + w3[base + 192 + i]; }
        else if (blk == 5)  { v2 = w2[base + 160 + i];                        v3 = w3[base + 160 + i]; }
        else                { v2 = w2[base + 224 + i];                        v3 = w3[base + 224 + i]; }
        wf2[idx] = v2;
        wf3[idx] = v3;
    }
}

// ---------------- 1x1 conv with 16-deep load ring ----------------
// MODE 0: write 32ch; MODE 2: relu + dot(w_out) -> 1ch (fused conv3+conv_out)
template<int CIN, int MODE>
__global__ __launch_bounds__(256) void conv1x1_k(const float* __restrict__ in,
                                                 const float* __restrict__ wt,   // [CIN][32]
                                                 const float* __restrict__ bias, // [32]
                                                 const float* __restrict__ wo,   // [32] (MODE 2)
                                                 float* __restrict__ out) {
    int p = blockIdx.x * 256 + threadIdx.x;
    int b = blockIdx.y;
    const float* ip = in + (size_t)b * CIN * HW + p;
    float acc[32];
#pragma unroll
    for (int o = 0; o < 32; ++o) acc[o] = bias[o];
    constexpr int PF = 16;
    float rbuf[PF];
#pragma unroll
    for (int j = 0; j < PF; ++j) rbuf[j] = ip[(size_t)j * HW];
#pragma unroll 1
    for (int i0 = 0; i0 < CIN - PF; i0 += PF) {
        const float* ipn = ip + (size_t)(i0 + PF) * HW;
        const float* wr0 = wt + i0 * 32;
#pragma unroll
        for (int j = 0; j < PF; ++j) {
            float v = rbuf[j];
            rbuf[j] = ipn[(size_t)j * HW];      // keep PF loads in flight
#pragma unroll
            for (int o = 0; o < 32; ++o) acc[o] = fmaf(wr0[j * 32 + o], v, acc[o]);
        }
    }
    const float* wrL = wt + (CIN - PF) * 32;
#pragma unroll
    for (int j = 0; j < PF; ++j) {
        float v = rbuf[j];
#pragma unroll
        for (int o = 0; o < 32; ++o) acc[o] = fmaf(wrL[j * 32 + o], v, acc[o]);
    }
    if (MODE == 2) {
        float m = 0.f;
#pragma unroll
        for (int o = 0; o < 32; ++o) m = fmaf(wo[o], frelu(acc[o]), m);
        out[(size_t)b * HW + p] = m;
    } else {
        float* op = out + (size_t)b * 32 * HW + p;
#pragma unroll
        for (int o = 0; o < 32; ++o) op[(size_t)o * HW] = acc[o];
    }
}

// ---------------- merged scan kernel: all 7 directional scans in one launch ----------------
// grid (80, K), 256 threads.
//   bx 0..7  : row forward,  4 waves = channels bx*4 .. bx*4+3   (down, diagDR, diagDL)
//   bx 8..15 : row backward, 4 waves = channels (bx-8)*4 ..      (up, diagUR)
//   bx 16..79: col scans, (bx-16)>>5 = dir (0 right,1 left), (bx-16)&31 = channel
__global__ __launch_bounds__(256) void scan_all(const float* __restrict__ F,   // [Kb][32][HW]
                                                float* __restrict__ CAT,       // [Kb][7][32][HW]
                                                const float* __restrict__ irw) {
    int b = blockIdx.y;
    int bx = blockIdx.x;
    __shared__ float tile[256 * 33];
    const float wd = irw[2];

    if (bx < 16) {
        // ---- row scans: one wave per channel, 4 cols/thread, shfl diag exchange ----
        int dirb = bx >> 3;
        int wave = threadIdx.x >> 6;
        int t = threadIdx.x & 63;
        int c = (bx & 7) * 4 + wave;
        const float4* xr = (const float4*)(F + ((size_t)b * 32 + c) * HW);
        size_t catbase = (size_t)b * 7 * 32 * HW + (size_t)c * HW;
        constexpr int D = 8;
        float4 buf[D];

        if (dirb == 0) {   // forward: down(2), diagDR(4), diagDL(5)
            float4* o_dn = (float4*)(CAT + catbase + (size_t)2 * 32 * HW);
            float4* o_dr = (float4*)(CAT + catbase + (size_t)4 * 32 * HW);
            float4* o_dl = (float4*)(CAT + catbase + (size_t)5 * 32 * HW);
            float4 x0 = xr[t];
            o_dn[t] = x0; o_dr[t] = x0; o_dl[t] = x0;
            float dn0=x0.x, dn1=x0.y, dn2=x0.z, dn3=x0.w;
            float dr0=x0.x, dr1=x0.y, dr2=x0.z, dr3=x0.w;
            float dl0=x0.x, dl1=x0.y, dl2=x0.z, dl3=x0.w;
#pragma unroll
            for (int j = 0; j < D; ++j) buf[j] = xr[(1 + j) * 64 + t];
            for (int hb = 1; hb < HD; hb += D) {
#pragma unroll
                for (int j = 0; j < D; ++j) {
                    int h = hb + j;
                    if (h < HD) {
                        float4 xv = buf[j];
                        int hn = h + D; if (hn > HD - 1) hn = HD - 1;
                        buf[j] = xr[hn * 64 + t];
                        float nbL = __shfl_up(dr3, 1);
                        float nbR = __shfl_down(dl0, 1);
                        dn0 = frelu(fmaf(dn0, wd, xv.x));
                        dn1 = frelu(fmaf(dn1, wd, xv.y));
                        dn2 = frelu(fmaf(dn2, wd, xv.z));
                        dn3 = frelu(fmaf(dn3, wd, xv.w));
                        float a0 = (t == 0) ? xv.x : frelu(fmaf(nbL, wd, xv.x));
                        float a1 = frelu(fmaf(dr0, wd, xv.y));
                        float a2 = frelu(fmaf(dr1, wd, xv.z));
                        float a3 = frelu(fmaf(dr2, wd, xv.w));
                        dr0 = a0; dr1 = a1; dr2 = a2; dr3 = a3;
                        float e0 = frelu(fmaf(dl1, wd, xv.x));
                        float e1 = frelu(fmaf(dl2, wd, xv.y));
                        float e2 = frelu(fmaf(dl3, wd, xv.z));
                        float e3 = (t == 63) ? xv.w : frelu(fmaf(nbR, wd, xv.w));
                        dl0 = e0; dl1 = e1; dl2 = e2; dl3 = e3;
                        o_dn[h * 64 + t] = make_float4(dn0, dn1, dn2, dn3);
                        o_dr[h * 64 + t] = make_float4(a0, a1, a2, a3);
                        o_dl[h * 64 + t] = make_float4(e0, e1, e2, e3);
                    }
                }
            }
        } else {           // backward: up(0), diagUR(6)
            const float wu = irw[0];
            float4* o_up = (float4*)(CAT + catbase + (size_t)0 * 32 * HW);
            float4* o_ur = (float4*)(CAT + catbase + (size_t)6 * 32 * HW);
            float4 x0 = xr[(HD - 1) * 64 + t];
            o_up[(HD - 1) * 64 + t] = x0; o_ur[(HD - 1) * 64 + t] = x0;
            float up0=x0.x, up1=x0.y, up2=x0.z, up3=x0.w;
            float ur0=x0.x, ur1=x0.y, ur2=x0.z, ur3=x0.w;
#pragma unroll
            for (int j = 0; j < D; ++j) buf[j] = xr[(HD - 2 - j) * 64 + t];
            for (int hb = HD - 2; hb >= 0; hb -= D) {
#pragma unroll
                for (int j = 0; j < D; ++j) {
                    int h = hb - j;
                    if (h >= 0) {
                        float4 xv = buf[j];
                        int hn = h - D; if (hn < 0) hn = 0;
                        buf[j] = xr[hn * 64 + t];
                        float nbL = __shfl_up(ur3, 1);
                        up0 = frelu(fmaf(up0, wu, xv.x));
                        up1 = frelu(fmaf(up1, wu, xv.y));
                        up2 = frelu(fmaf(up2, wu, xv.z));
                        up3 = frelu(fmaf(up3, wu, xv.w));
                        float a0 = (t == 0) ? xv.x : frelu(fmaf(nbL, wd, xv.x));
                        float a1 = frelu(fmaf(ur0, wd, xv.y));
                        float a2 = frelu(fmaf(ur1, wd, xv.z));
                        float a3 = frelu(fmaf(ur2, wd, xv.w));
                        ur0 = a0; ur1 = a1; ur2 = a2; ur3 = a3;
                        o_up[h * 64 + t] = make_float4(up0, up1, up2, up3);
                        o_ur[h * 64 + t] = make_float4(a0, a1, a2, a3);
                    }
                }
            }
        }
    } else {
        // ---- col scans: right(1)/left(3), LDS-tiled, double-buffered ----
        int i = bx - 16;
        int dir = i >> 5;
        int c = i & 31;
        int t = threadIdx.x;
        const float wgt = (dir == 0) ? irw[1] : irw[3];
        const float* x = F + ((size_t)b * 32 + c) * HW;
        float* o = CAT + ((size_t)b * 7 + (dir == 0 ? 1 : 3)) * 32 * HW + (size_t)c * HW;
        int hh0 = t >> 5, ww = t & 31;
        float r[2][32];
        float carry = 0.f;
        {
            int wb0 = (dir == 0) ? 0 : 7 * 32;
#pragma unroll
            for (int k = 0; k < 32; ++k)
                r[0][k] = x[(k * 8 + hh0) * WD + wb0 + ww];
        }
#pragma unroll
        for (int tw = 0; tw < 8; ++tw) {
            int wbase = (dir == 0) ? tw * 32 : (7 - tw) * 32;
            const int cur = tw & 1, nxt = cur ^ 1;
            __syncthreads();
#pragma unroll
            for (int k = 0; k < 32; ++k)
                tile[(k * 8 + hh0) * 33 + ww] = r[cur][k];
            __syncthreads();
            if (tw < 7) {
                int wb2 = (dir == 0) ? (tw + 1) * 32 : (6 - tw) * 32;
#pragma unroll
                for (int k = 0; k < 32; ++k)
                    r[nxt][k] = x[(k * 8 + hh0) * WD + wb2 + ww];
            }
            if (dir == 0) {
#pragma unroll
                for (int j = 0; j < 32; ++j) {
                    float xv = tile[t * 33 + j];
                    carry = (wbase + j == 0) ? xv : frelu(fmaf(carry, wgt, xv));
                    tile[t * 33 + j] = carry;
                }
            } else {
#pragma unroll
                for (int j = 31; j >= 0; --j) {
                    float xv = tile[t * 33 + j];
                    carry = (wbase + j == WD - 1) ? xv : frelu(fmaf(carry, wgt, xv));
                    tile[t * 33 + j] = carry;
                }
            }
            __syncthreads();
#pragma unroll
            for (int k = 0; k < 32; ++k)
                o[(k * 8 + hh0) * WD + wbase + ww] = tile[(k * 8 + hh0) * 33 + ww];
        }
    }
}

extern "C" void kernel_launch(void* const* d_in, const int* in_sizes, int n_in,
                              void* d_out, int out_size, void* d_ws, size_t ws_size,
                              hipStream_t stream) {
    const float* x    = (const float*)d_in[0];
    const float* w1   = (const float*)d_in[1];
    const float* b1   = (const float*)d_in[2];
    const float* w2   = (const float*)d_in[3];
    const float* b2   = (const float*)d_in[4];
    const float* w3   = (const float*)d_in[5];
    const float* b3   = (const float*)d_in[6];
    const float* wout = (const float*)d_in[7];
    const float* ir1  = (const float*)d_in[8];
    const float* ir2  = (const float*)d_in[9];

    const size_t fbytes = (size_t)CC * HW * sizeof(float);  // 8 MB per batch-image
    const size_t wbytes = (64 * 32 + 2 * 224 * 32) * sizeof(float);

    // need K*(1 F + 7 CAT)*8MB + weights   (F is reused for conv1 and conv2 outputs)
    int K = 4;
    while (K > 1 && ((size_t)K * 8 * fbytes + wbytes) > ws_size) K >>= 1;

    char* ws = (char*)d_ws;
    float* F   = (float*)ws;  ws += (size_t)K * fbytes;
    float* CAT = (float*)ws;  ws += (size_t)K * 7 * fbytes;
    float* WT1 = (float*)ws;  ws += 64 * 32 * sizeof(float);
    float* WF2 = (float*)ws;  ws += 224 * 32 * sizeof(float);
    float* WF3 = (float*)ws;

    prep_weights<<<1, 256, 0, stream>>>(w1, w2, w3, WT1, WF2, WF3);

    for (int b0 = 0; b0 < 4; b0 += K) {
        conv1x1_k<64, 0><<<dim3(HW / 256, K), 256, 0, stream>>>(
            x + (size_t)b0 * 64 * HW, WT1, b1, nullptr, F);
        scan_all<<<dim3(80, K), 256, 0, stream>>>(F, CAT, ir1);
        conv1x1_k<224, 0><<<dim3(HW / 256, K), 256, 0, stream>>>(CAT, WF2, b2, nullptr, F);
        scan_all<<<dim3(80, K), 256, 0, stream>>>(F, CAT, ir2);
        conv1x1_k<224, 2><<<dim3(HW / 256, K), 256, 0, stream>>>(
            CAT, WF3, b3, wout, (float*)d_out + (size_t)b0 * HW);
    }
}